// Round 9
// baseline (265.490 us; speedup 1.0000x reference)
//
#include <hip/hip_runtime.h>
#include <math.h>

// Qwen3 MoE sparse block, MI355X/gfx950.
// Sizes fixed by the reference: T=2048 tokens, H=1024, E=16, I=512, top-4.
constexpr int TT = 2048;   // tokens
constexpr int HH = 1024;   // hidden
constexpr int EE = 16;     // experts
constexpr int II = 512;    // intermediate

typedef unsigned short u16;
typedef short s16x8 __attribute__((ext_vector_type(8)));   // 8 bf16 for MFMA A/B
typedef float f32x4 __attribute__((ext_vector_type(4)));   // MFMA C/D

__device__ __forceinline__ u16 f2bf(float f) {
  unsigned u = __float_as_uint(f);
  u = (u + 0x7fffu + ((u >> 16) & 1u)) >> 16;   // round-to-nearest-even
  return (u16)u;
}
__device__ __forceinline__ float bf2f(u16 b) {
  return __uint_as_float(((unsigned)b) << 16);
}

// async global->LDS, 16B per lane; lds base must be wave-uniform (HW adds lane*16)
__device__ __forceinline__ void gl2lds16(const void* g, void* l) {
  __builtin_amdgcn_global_load_lds(
      (const __attribute__((address_space(1))) unsigned*)g,
      (__attribute__((address_space(3))) unsigned*)l, 16, 0, 0);
}

// 4x4 transpose within lane quads (proven correct in R7's prep).
// In: v[j] = M[li][j]. Out: v[j] = M[j][li].
__device__ __forceinline__ void tr4(float4& v, int li) {
  float t, r;
  t = (li & 1) ? v.x : v.y; r = __shfl_xor(t, 1);
  if (li & 1) v.x = r; else v.y = r;
  t = (li & 1) ? v.z : v.w; r = __shfl_xor(t, 1);
  if (li & 1) v.z = r; else v.w = r;
  t = (li & 2) ? v.x : v.z; r = __shfl_xor(t, 2);
  if (li & 2) v.x = r; else v.z = r;
  t = (li & 2) ? v.y : v.w; r = __shfl_xor(t, 2);
  if (li & 2) v.y = r; else v.w = r;
}

// Stage one 64n x 8k strip of an fp32 [k][n] matrix into swizzled [n][k] bf16 LDS.
// lane: li=lane&3 (row within quad), q=lane>>2 (n-quad). R8: this replaces the
// standalone weight-transpose pass entirely (three prep variants all capped at
// ~2.5 TB/s; fusing into GEMM staging removes the intermediate altogether).
__device__ __forceinline__ void stageB(const float* __restrict__ src, int ldn,
                                       int krow, int ncol, int g, u16* lds,
                                       int li, int q) {
  const float* p = src + (size_t)krow * ldn + ncol + 4 * q;
  float4 a = *reinterpret_cast<const float4*>(p);
  float4 b = *reinterpret_cast<const float4*>(p + 4 * ldn);
  tr4(a, li); tr4(b, li);   // lane li: k = krow-li .. +3 (a), +4..+7 (b) at n = ncol+4q+li
  uint4 st;
  st.x = (unsigned)f2bf(a.x) | ((unsigned)f2bf(a.y) << 16);
  st.y = (unsigned)f2bf(a.z) | ((unsigned)f2bf(a.w) << 16);
  st.z = (unsigned)f2bf(b.x) | ((unsigned)f2bf(b.y) << 16);
  st.w = (unsigned)f2bf(b.z) | ((unsigned)f2bf(b.w) << 16);
  int n = 4 * q + li;                       // n within the 64-row LDS strip
  *reinterpret_cast<uint4*>(&lds[n * 64 + ((g ^ (n & 7)) << 3)]) = st;
}

// ---------------- prep: cast x fp32->bf16 + transpose wg -> wgT [E][H] fp32 ----------------
__global__ void prep_kernel(const float* __restrict__ x, u16* __restrict__ xb,
                            const float* __restrict__ wg, float* __restrict__ wgT) {
  int b = blockIdx.x;
  if (b < 2048) {
    int i = b * 256 + threadIdx.x;
    float4 v = reinterpret_cast<const float4*>(x)[i];
    ushort4 o;
    o.x = f2bf(v.x); o.y = f2bf(v.y); o.z = f2bf(v.z); o.w = f2bf(v.w);
    reinterpret_cast<ushort4*>(xb)[i] = o;
  } else {
    int i = (b - 2048) * 256 + threadIdx.x;
    int h = i >> 4, e = i & 15;
    wgT[e * HH + h] = wg[i];
  }
}

// ---------------- router: logits, top-4, per-token sel/weights. NO atomics. ----------------
__global__ void router_kernel(const float* __restrict__ x, const float* __restrict__ wgT,
                              float* __restrict__ rl, unsigned* __restrict__ selmask,
                              float* __restrict__ wsel) {
  int lane = threadIdx.x & 63, wv = threadIdx.x >> 6;
  int t = blockIdx.x * 4 + wv;          // one wave per token
  const float* xr = x + (size_t)t * HH;
  float xv[16];
#pragma unroll
  for (int i = 0; i < 16; ++i) xv[i] = xr[lane + 64 * i];
  float lg[16];
#pragma unroll
  for (int e = 0; e < 16; ++e) {
    const float* wr = wgT + (size_t)e * HH;
    float p = 0.f;
#pragma unroll
    for (int i = 0; i < 16; ++i) p += xv[i] * wr[lane + 64 * i];
#pragma unroll
    for (int s = 32; s > 0; s >>= 1) p += __shfl_xor(p, s, 64);
    lg[e] = p;   // all lanes hold the full logit after butterfly
  }
  if (lane < 16) rl[(size_t)t * 16 + lane] = lg[lane];
  // top-4 (stable: earlier index wins ties, matches lax.top_k)
  unsigned mask = 0;
  int sel[4]; float bl[4];
#pragma unroll
  for (int k = 0; k < 4; ++k) {
    float best = -3.4e38f; int bi = 0;
#pragma unroll
    for (int e = 0; e < 16; ++e) {
      bool ok = !((mask >> e) & 1u) && (lg[e] > best);
      best = ok ? lg[e] : best;
      bi = ok ? e : bi;
    }
    mask |= 1u << bi;
    sel[k] = bi; bl[k] = best;
  }
  // normalized top-k softmax: full denominator cancels
  float mx = bl[0];
  float wk[4]; float s = 0.f;
#pragma unroll
  for (int k = 0; k < 4; ++k) { wk[k] = expf(bl[k] - mx); s += wk[k]; }
  float inv = 1.f / s;
  if (lane == 0) {
    selmask[t] = (unsigned)sel[0] | ((unsigned)sel[1] << 4) |
                 ((unsigned)sel[2] << 8) | ((unsigned)sel[3] << 12);
    float4 w4 = make_float4(wk[0] * inv, wk[1] * inv, wk[2] * inv, wk[3] * inv);
    reinterpret_cast<float4*>(wsel)[t] = w4;
  }
}

// ---------------- build per-expert lists: 1 block, 16 waves, ballot-compaction ----------------
__global__ void build_lists_kernel(const unsigned* __restrict__ selmask,
                                   const float* __restrict__ wsel,
                                   int* __restrict__ counts, int* __restrict__ offsets,
                                   int* __restrict__ tlist, float* __restrict__ wlist,
                                   int* __restrict__ rowof) {
  __shared__ int scnt[16];
  __shared__ int soff[16];
  int lane = threadIdx.x & 63, e = threadIdx.x >> 6;   // wave e handles expert e
  // pass 1: count only
  int base = 0;
  for (int t0 = 0; t0 < TT; t0 += 64) {
    unsigned m = selmask[t0 + lane];
    bool hit = false;
#pragma unroll
    for (int j = 0; j < 4; ++j)
      hit |= (((m >> (4 * j)) & 15u) == (unsigned)e);
    base += (int)__popcll(__ballot(hit));
  }
  if (lane == 0) scnt[e] = base;
  __syncthreads();
  if (threadIdx.x == 0) {
    int s = 0;
    for (int i = 0; i < 16; ++i) { counts[i] = scnt[i]; offsets[i] = s; soff[i] = s; s += scnt[i]; }
    offsets[16] = s;
  }
  __syncthreads();
  // pass 2: write compacted lists + inverse map
  int hb = soff[e];
  base = 0;
  for (int t0 = 0; t0 < TT; t0 += 64) {
    int t = t0 + lane;
    unsigned m = selmask[t];
    int k = -1;
#pragma unroll
    for (int j = 0; j < 4; ++j)
      if (((m >> (4 * j)) & 15u) == (unsigned)e) k = j;
    unsigned long long bal = __ballot(k >= 0);
    int pos = base + (int)__popcll(bal & ((1ull << lane) - 1ull));
    if (k >= 0) {
      tlist[e * TT + pos] = t;
      wlist[e * TT + pos] = wsel[t * 4 + k];
      rowof[t * 4 + k] = hb + pos;
    }
    base += (int)__popcll(bal);
  }
}

// ---------------- gate+up fused GEMM -> hidden (bf16, pre-scaled by routing weight) ----------------
// Tile 128(M)x64(N), BK=64, swizzled LDS, 4 waves 2x2 (wave = 64 rows x 32 cols).
// R8: B tiles staged straight from fp32 [k][n] weights via tr4 + ds_write_b128.
__global__ __launch_bounds__(256, 2) void gateup_kernel(
    const u16* __restrict__ xb, const float* __restrict__ wgp, const float* __restrict__ wup,
    const int* __restrict__ counts, const int* __restrict__ offsets,
    const int* __restrict__ tlist, const float* __restrict__ wlist,
    u16* __restrict__ hidden) {
  int e = blockIdx.z, mt = blockIdx.y, nt = blockIdx.x;   // nt 0..7 (64 cols each)
  int cnt = counts[e];
  if (mt * 128 >= cnt) return;
  __shared__ u16 As[128 * 64];   // [m][k] swizzled
  __shared__ u16 Bg[64 * 64];    // [n][k] swizzled
  __shared__ u16 Bu[64 * 64];
  int tid = threadIdx.x, lane = tid & 63, wv = tid >> 6;
  int wm = wv >> 1, wn = wv & 1;
  int srow = lane >> 3;                     // staging row within 8-row chunk
  int scol = (((lane & 7) ^ srow)) * 8;     // swizzled global k-offset (u16)
  int li = lane & 3, q = lane >> 2;
  const float* wgE = wgp + (size_t)e * HH * II;
  const float* wuE = wup + (size_t)e * HH * II;
  // A: 16 chunks of 8 rows, chunk = c*4+wv, via global_load_lds
  const u16* gA[4];
#pragma unroll
  for (int c = 0; c < 4; ++c) {
    int chunk = c * 4 + wv;
    int mi = mt * 128 + chunk * 8 + srow; if (mi >= cnt) mi = cnt - 1;
    int tok = tlist[e * TT + mi];
    gA[c] = xb + (size_t)tok * HH + scol;
  }
  f32x4 accG[4][2] = {}; f32x4 accU[4][2] = {};
  int quad = lane >> 4, colc = lane & 15;
  for (int k0 = 0; k0 < HH; k0 += 64) {
#pragma unroll
    for (int c = 0; c < 4; ++c)
      gl2lds16(gA[c] + k0, &As[(c * 4 + wv) * 512]);
    // B: 16 units (matrix x 8 k-groups); unit = wv*4 + p
#pragma unroll
    for (int p = 0; p < 4; ++p) {
      int unit = wv * 4 + p;
      int g = unit & 7;
      const float* src = (unit >> 3) ? wuE : wgE;
      u16* lds = (unit >> 3) ? Bu : Bg;
      stageB(src, II, k0 + g * 8 + li, nt * 64, g, lds, li, q);
    }
    __syncthreads();
#pragma unroll
    for (int kk = 0; kk < 64; kk += 32) {
      int gl = (kk >> 3) + quad;            // logical k-group
      s16x8 a[4], bg[2], bu[2];
#pragma unroll
      for (int f = 0; f < 4; ++f) {
        int m = wm * 64 + f * 16 + colc;
        a[f] = *reinterpret_cast<const s16x8*>(&As[m * 64 + ((gl ^ (m & 7)) << 3)]);
      }
#pragma unroll
      for (int f = 0; f < 2; ++f) {
        int n = wn * 32 + f * 16 + colc;
        bg[f] = *reinterpret_cast<const s16x8*>(&Bg[n * 64 + ((gl ^ (n & 7)) << 3)]);
        bu[f] = *reinterpret_cast<const s16x8*>(&Bu[n * 64 + ((gl ^ (n & 7)) << 3)]);
      }
#pragma unroll
      for (int fm = 0; fm < 4; ++fm)
#pragma unroll
        for (int fn = 0; fn < 2; ++fn) {
          accG[fm][fn] = __builtin_amdgcn_mfma_f32_16x16x32_bf16(a[fm], bg[fn], accG[fm][fn], 0, 0, 0);
          accU[fm][fn] = __builtin_amdgcn_mfma_f32_16x16x32_bf16(a[fm], bu[fn], accU[fm][fn], 0, 0, 0);
        }
    }
    __syncthreads();
  }
  // epilogue: hidden = w_route * silu(g) * u   (C/D: col=lane&15, row=quad*4+reg)
  int hb = offsets[e];
#pragma unroll
  for (int fm = 0; fm < 4; ++fm) {
#pragma unroll
    for (int r = 0; r < 4; ++r) {
      int mi = mt * 128 + wm * 64 + fm * 16 + quad * 4 + r;
      if (mi < cnt) {
        float wr = wlist[e * TT + mi];
        u16* hrow = hidden + (size_t)(hb + mi) * II + nt * 64 + wn * 32;
#pragma unroll
        for (int fn = 0; fn < 2; ++fn) {
          float g = accG[fm][fn][r], u = accU[fm][fn][r];
          float hval = wr * u * g / (1.f + expf(-g));
          hrow[fn * 16 + colc] = f2bf(hval);
        }
      }
    }
  }
}

// ---------------- down GEMM: hidden @ wd -> dense bf16 rows in dtmp (no atomics) ----------------
// Tile 128x128, BK=64; B staged from fp32 wd [i][h] via tr4 + ds_write_b128.
__global__ __launch_bounds__(256, 2) void down_kernel(
    const u16* __restrict__ hidden, const float* __restrict__ wdp,
    const int* __restrict__ counts, const int* __restrict__ offsets,
    u16* __restrict__ dtmp) {
  int e = blockIdx.z, mt = blockIdx.y, nt = blockIdx.x;
  int cnt = counts[e];
  if (mt * 128 >= cnt) return;
  int hb = offsets[e];
  __shared__ u16 As[128 * 64];
  __shared__ u16 Bs[128 * 64];
  int tid = threadIdx.x, lane = tid & 63, wv = tid >> 6;
  int wm = wv >> 1, wn = wv & 1;
  int srow = lane >> 3;
  int scol = (((lane & 7) ^ srow)) * 8;     // swizzled global k-offset
  int li = lane & 3, q = lane >> 2;
  const float* wdE = wdp + (size_t)e * II * HH;
  const u16* gA[4];
#pragma unroll
  for (int c = 0; c < 4; ++c) {
    int chunk = c * 4 + wv;
    int row = hb + mt * 128 + chunk * 8 + srow;
    if (row > 8191) row = 8191;   // clamp pad rows into the hidden buffer
    gA[c] = hidden + (size_t)row * II + scol;
  }
  f32x4 acc[4][4] = {};
  int quad = lane >> 4, colc = lane & 15;
  for (int k0 = 0; k0 < II; k0 += 64) {
#pragma unroll
    for (int c = 0; c < 4; ++c)
      gl2lds16(gA[c] + k0, &As[(c * 4 + wv) * 512]);
    // B: 16 units (2 n-blocks x 8 k-groups); unit = wv*4 + p
#pragma unroll
    for (int p = 0; p < 4; ++p) {
      int unit = wv * 4 + p;
      int g = unit & 7;
      int nb = unit >> 3;
      stageB(wdE, HH, k0 + g * 8 + li, nt * 128 + nb * 64, g, &Bs[nb * 64 * 64], li, q);
    }
    __syncthreads();
#pragma unroll
    for (int kk = 0; kk < 64; kk += 32) {
      int gl = (kk >> 3) + quad;
      s16x8 a[4], b[4];
#pragma unroll
      for (int f = 0; f < 4; ++f) {
        int m = wm * 64 + f * 16 + colc;
        int n = wn * 64 + f * 16 + colc;
        a[f] = *reinterpret_cast<const s16x8*>(&As[m * 64 + ((gl ^ (m & 7)) << 3)]);
        b[f] = *reinterpret_cast<const s16x8*>(&Bs[n * 64 + ((gl ^ (n & 7)) << 3)]);
      }
#pragma unroll
      for (int fm = 0; fm < 4; ++fm)
#pragma unroll
        for (int fn = 0; fn < 4; ++fn)
          acc[fm][fn] = __builtin_amdgcn_mfma_f32_16x16x32_bf16(a[fm], b[fn], acc[fm][fn], 0, 0, 0);
    }
    __syncthreads();
  }
#pragma unroll
  for (int fm = 0; fm < 4; ++fm) {
#pragma unroll
    for (int r = 0; r < 4; ++r) {
      int mi = mt * 128 + wm * 64 + fm * 16 + quad * 4 + r;
      if (mi < cnt) {
        u16* drow = dtmp + (size_t)(hb + mi) * HH + nt * 128 + wn * 64;
#pragma unroll
        for (int fn = 0; fn < 4; ++fn)
          drow[fn * 16 + colc] = f2bf(acc[fm][fn][r]);
      }
    }
  }
}

// ---------------- combine: out[t] = sum of 4 expert rows (routing weight already applied) ----------------
__global__ void combine_kernel(const u16* __restrict__ dtmp, const int* __restrict__ rowof,
                               float* __restrict__ out) {
  int t = blockIdx.x, tid = threadIdx.x;
  int4 rw = reinterpret_cast<const int4*>(rowof)[t];
  int h = tid * 4;
  float s0 = 0.f, s1 = 0.f, s2 = 0.f, s3 = 0.f;
  int rows[4] = {rw.x, rw.y, rw.z, rw.w};
#pragma unroll
  for (int k = 0; k < 4; ++k) {
    ushort4 v = *reinterpret_cast<const ushort4*>(&dtmp[(size_t)rows[k] * HH + h]);
    s0 += bf2f(v.x); s1 += bf2f(v.y); s2 += bf2f(v.z); s3 += bf2f(v.w);
  }
  *reinterpret_cast<float4*>(&out[(size_t)t * HH + h]) = make_float4(s0, s1, s2, s3);
}

extern "C" void kernel_launch(void* const* d_in, const int* in_sizes, int n_in,
                              void* d_out, int out_size, void* d_ws, size_t ws_size,
                              hipStream_t stream) {
  const float* x   = (const float*)d_in[0];   // [1,2048,1024]
  const float* wg  = (const float*)d_in[1];   // [1024,16]
  const float* wgp = (const float*)d_in[2];   // [16,1024,512]
  const float* wup = (const float*)d_in[3];   // [16,1024,512]
  const float* wdp = (const float*)d_in[4];   // [16,512,1024]
  float* out = (float*)d_out;                 // [2048*1024] then router_logits [2048*16]
  float* rl  = out + (size_t)TT * HH;

  char* w = (char*)d_ws;
  int*      counts  = (int*)(w + 0);                  // 16 ints
  int*      offsets = (int*)(w + 64);                 // 17 ints
  unsigned* selmask = (unsigned*)(w + 1024);          // [T] packed 4x4-bit expert ids
  float*    wsel    = (float*)(w + 16384);            // [T][4] normalized weights (32 KB)
  int*      rowof   = (int*)(w + 49152);              // [T][4] global hidden-row ids (32 KB)
  int*      tlist   = (int*)(w + 81920);              // [E][T] token ids (128 KB)
  float*    wlist   = (float*)(w + 210944);           // [E][T] routing weights (128 KB)
  float*    wgT     = (float*)(w + 339968);           // [E][H] fp32 transposed router weights
  u16*      xb      = (u16*)(w + 405504);             // [T][H] bf16 (4 MB)
  u16*      hidden  = xb + (size_t)TT * HH;           // [8192][I] bf16 (8 MB)
  u16*      dtmp    = hidden + (size_t)4 * TT * II;   // [8192][H] bf16 (16 MB)

  hipLaunchKernelGGL(prep_kernel, dim3(2048 + 64), dim3(256), 0, stream,
                     x, xb, wg, wgT);
  hipLaunchKernelGGL(router_kernel, dim3(TT / 4), dim3(256), 0, stream,
                     x, wgT, rl, selmask, wsel);
  hipLaunchKernelGGL(build_lists_kernel, dim3(1), dim3(1024), 0, stream,
                     selmask, wsel, counts, offsets, tlist, wlist, rowof);
  hipLaunchKernelGGL(gateup_kernel, dim3(8, 16, 16), dim3(256), 0, stream,
                     xb, wgp, wup, counts, offsets, tlist, wlist, hidden);
  hipLaunchKernelGGL(down_kernel, dim3(8, 16, 16), dim3(256), 0, stream,
                     hidden, wdp, counts, offsets, dtmp);
  hipLaunchKernelGGL(combine_kernel, dim3(TT), dim3(256), 0, stream,
                     dtmp, rowof, out);
}

// Round 10
// 234.036 us; speedup vs baseline: 1.1344x; 1.1344x over previous
//
#include <hip/hip_runtime.h>
#include <math.h>

// Qwen3 MoE sparse block, MI355X/gfx950.
// Sizes fixed by the reference: T=2048 tokens, H=1024, E=16, I=512, top-4.
constexpr int TT = 2048;   // tokens
constexpr int HH = 1024;   // hidden
constexpr int EE = 16;     // experts
constexpr int II = 512;    // intermediate

typedef unsigned short u16;
typedef short s16x8 __attribute__((ext_vector_type(8)));   // 8 bf16 for MFMA A/B
typedef float f32x4 __attribute__((ext_vector_type(4)));   // MFMA C/D

__device__ __forceinline__ u16 f2bf(float f) {
  unsigned u = __float_as_uint(f);
  u = (u + 0x7fffu + ((u >> 16) & 1u)) >> 16;   // round-to-nearest-even
  return (u16)u;
}
__device__ __forceinline__ float bf2f(u16 b) {
  return __uint_as_float(((unsigned)b) << 16);
}

// async global->LDS, 16B per lane; lds base must be wave-uniform (HW adds lane*16)
__device__ __forceinline__ void gl2lds16(const void* g, void* l) {
  __builtin_amdgcn_global_load_lds(
      (const __attribute__((address_space(1))) unsigned*)g,
      (__attribute__((address_space(3))) unsigned*)l, 16, 0, 0);
}

// ---------------- prep mega-kernel: weight transpose v4 + cast x + wgT ----------------
// v4 (R6, best measured 42.9us): tile 64n x 32k, lane owns 1n x 8k. Store instr =
// 16 rows x 64B granules. R9 lesson: fusing the transpose into GEMM staging is 4x
// worse (shuffle+cvt chain serializes with MFMA) — keep it standalone.
__global__ __launch_bounds__(256) void prep_kernel(
    const float* __restrict__ wgp, const float* __restrict__ wup,
    const float* __restrict__ wdp, u16* __restrict__ wgt,
    u16* __restrict__ wut, u16* __restrict__ wdt,
    const float* __restrict__ x, u16* __restrict__ xb,
    const float* __restrict__ wg, float* __restrict__ wgT) {
  int bid = blockIdx.x;
  int tid = threadIdx.x;
  if (bid < 12288) {
    // ---- weight transpose: 48 regions x 256 blocks ----
    int z = bid >> 8, lb = bid & 255;
    int e = z & 15, t = z >> 4;
    const float* src; u16* dst; int K, N;
    if (t == 0)      { src = wgp + (size_t)e * HH * II; dst = wgt + (size_t)e * II * HH; K = HH; N = II; }
    else if (t == 1) { src = wup + (size_t)e * HH * II; dst = wut + (size_t)e * II * HH; K = HH; N = II; }
    else             { src = wdp + (size_t)e * II * HH; dst = wdt + (size_t)e * HH * II; K = II; N = HH; }
    int nTiles = N >> 6;                 // 64-wide n tiles
    int n0 = (lb % nTiles) * 64;
    int k0 = (lb / nTiles) * 32;         // 32-deep k tiles
    int l = tid & 63, w = tid >> 6;
    int n  = n0 + w * 16 + (l >> 2);     // 1 n per thread
    int kc = l & 3;                      // k-chunk: 8 consecutive k
    float v[8];
#pragma unroll
    for (int j = 0; j < 8; ++j)
      v[j] = src[(size_t)(k0 + kc * 8 + j) * N + n];
    uint4 st;
    st.x = (unsigned)f2bf(v[0]) | ((unsigned)f2bf(v[1]) << 16);
    st.y = (unsigned)f2bf(v[2]) | ((unsigned)f2bf(v[3]) << 16);
    st.z = (unsigned)f2bf(v[4]) | ((unsigned)f2bf(v[5]) << 16);
    st.w = (unsigned)f2bf(v[6]) | ((unsigned)f2bf(v[7]) << 16);
    *reinterpret_cast<uint4*>(&dst[(size_t)n * K + k0 + kc * 8]) = st;
  } else if (bid < 12288 + 2048) {
    // ---- cast x fp32 -> bf16 ----
    int i = (bid - 12288) * 256 + tid;
    float4 v = reinterpret_cast<const float4*>(x)[i];
    ushort4 o;
    o.x = f2bf(v.x); o.y = f2bf(v.y); o.z = f2bf(v.z); o.w = f2bf(v.w);
    reinterpret_cast<ushort4*>(xb)[i] = o;
  } else {
    // ---- transpose wg [H][E] -> wgT [E][H] fp32 (64 blocks) ----
    int i = (bid - 12288 - 2048) * 256 + tid;
    int h = i >> 4, e = i & 15;
    wgT[e * HH + h] = wg[i];
  }
}

// ---------------- router: logits, top-4, per-token sel/weights. NO atomics. ----------------
__global__ void router_kernel(const float* __restrict__ x, const float* __restrict__ wgT,
                              float* __restrict__ rl, unsigned* __restrict__ selmask,
                              float* __restrict__ wsel) {
  int lane = threadIdx.x & 63, wv = threadIdx.x >> 6;
  int t = blockIdx.x * 4 + wv;          // one wave per token
  const float* xr = x + (size_t)t * HH;
  float xv[16];
#pragma unroll
  for (int i = 0; i < 16; ++i) xv[i] = xr[lane + 64 * i];
  float lg[16];
#pragma unroll
  for (int e = 0; e < 16; ++e) {
    const float* wr = wgT + (size_t)e * HH;
    float p = 0.f;
#pragma unroll
    for (int i = 0; i < 16; ++i) p += xv[i] * wr[lane + 64 * i];
#pragma unroll
    for (int s = 32; s > 0; s >>= 1) p += __shfl_xor(p, s, 64);
    lg[e] = p;   // all lanes hold the full logit after butterfly
  }
  if (lane < 16) rl[(size_t)t * 16 + lane] = lg[lane];
  // top-4 (stable: earlier index wins ties, matches lax.top_k)
  unsigned mask = 0;
  int sel[4]; float bl[4];
#pragma unroll
  for (int k = 0; k < 4; ++k) {
    float best = -3.4e38f; int bi = 0;
#pragma unroll
    for (int e = 0; e < 16; ++e) {
      bool ok = !((mask >> e) & 1u) && (lg[e] > best);
      best = ok ? lg[e] : best;
      bi = ok ? e : bi;
    }
    mask |= 1u << bi;
    sel[k] = bi; bl[k] = best;
  }
  // normalized top-k softmax: full denominator cancels
  float mx = bl[0];
  float wk[4]; float s = 0.f;
#pragma unroll
  for (int k = 0; k < 4; ++k) { wk[k] = expf(bl[k] - mx); s += wk[k]; }
  float inv = 1.f / s;
  if (lane == 0) {
    selmask[t] = (unsigned)sel[0] | ((unsigned)sel[1] << 4) |
                 ((unsigned)sel[2] << 8) | ((unsigned)sel[3] << 12);
    float4 w4 = make_float4(wk[0] * inv, wk[1] * inv, wk[2] * inv, wk[3] * inv);
    reinterpret_cast<float4*>(wsel)[t] = w4;
  }
}

// ---------------- build per-expert lists: 1 block, 16 waves, ballot-compaction ----------------
__global__ void build_lists_kernel(const unsigned* __restrict__ selmask,
                                   const float* __restrict__ wsel,
                                   int* __restrict__ counts, int* __restrict__ offsets,
                                   int* __restrict__ tlist, float* __restrict__ wlist,
                                   int* __restrict__ rowof) {
  __shared__ int scnt[16];
  __shared__ int soff[16];
  int lane = threadIdx.x & 63, e = threadIdx.x >> 6;   // wave e handles expert e
  // pass 1: count only
  int base = 0;
  for (int t0 = 0; t0 < TT; t0 += 64) {
    unsigned m = selmask[t0 + lane];
    bool hit = false;
#pragma unroll
    for (int j = 0; j < 4; ++j)
      hit |= (((m >> (4 * j)) & 15u) == (unsigned)e);
    base += (int)__popcll(__ballot(hit));
  }
  if (lane == 0) scnt[e] = base;
  __syncthreads();
  if (threadIdx.x == 0) {
    int s = 0;
    for (int i = 0; i < 16; ++i) { counts[i] = scnt[i]; offsets[i] = s; soff[i] = s; s += scnt[i]; }
    offsets[16] = s;
  }
  __syncthreads();
  // pass 2: write compacted lists + inverse map
  int hb = soff[e];
  base = 0;
  for (int t0 = 0; t0 < TT; t0 += 64) {
    int t = t0 + lane;
    unsigned m = selmask[t];
    int k = -1;
#pragma unroll
    for (int j = 0; j < 4; ++j)
      if (((m >> (4 * j)) & 15u) == (unsigned)e) k = j;
    unsigned long long bal = __ballot(k >= 0);
    int pos = base + (int)__popcll(bal & ((1ull << lane) - 1ull));
    if (k >= 0) {
      tlist[e * TT + pos] = t;
      wlist[e * TT + pos] = wsel[t * 4 + k];
      rowof[t * 4 + k] = hb + pos;
    }
    base += (int)__popcll(bal);
  }
}

// ---------------- gate+up fused GEMM -> hidden (bf16, pre-scaled by routing weight) ----------------
// Tile 128(M)x64(N), BK=64, swizzled LDS. 4 waves 2x2: wave = 64 rows x 32 cols.
__global__ __launch_bounds__(256, 2) void gateup_kernel(
    const u16* __restrict__ xb, const u16* __restrict__ wgt, const u16* __restrict__ wut,
    const int* __restrict__ counts, const int* __restrict__ offsets,
    const int* __restrict__ tlist, const float* __restrict__ wlist,
    u16* __restrict__ hidden) {
  int e = blockIdx.z, mt = blockIdx.y, nt = blockIdx.x;   // nt 0..7 (64 cols each)
  int cnt = counts[e];
  if (mt * 128 >= cnt) return;
  __shared__ u16 As[128 * 64];   // [m][k] swizzled
  __shared__ u16 Bg[64 * 64];    // [n][k] swizzled
  __shared__ u16 Bu[64 * 64];
  int tid = threadIdx.x, lane = tid & 63, wv = tid >> 6;
  int wm = wv >> 1, wn = wv & 1;
  int srow = lane >> 3;                     // staging row within 8-row chunk
  int scol = (((lane & 7) ^ srow)) * 8;     // swizzled global k-offset (u16)
  const u16* wgE = wgt + (size_t)e * II * HH;
  const u16* wuE = wut + (size_t)e * II * HH;
  // 32 chunks of 8 rows: A=0..15, Bg=16..23, Bu=24..31; chunk = c*4+wv
  const u16* gp[8];
#pragma unroll
  for (int c = 0; c < 8; ++c) {
    int chunk = c * 4 + wv;
    const u16* p;
    if (chunk < 16) {
      int mi = mt * 128 + chunk * 8 + srow; if (mi >= cnt) mi = cnt - 1;
      int tok = tlist[e * TT + mi];
      p = xb + (size_t)tok * HH + scol;
    } else if (chunk < 24) {
      int n = nt * 64 + (chunk - 16) * 8 + srow;
      p = wgE + (size_t)n * HH + scol;
    } else {
      int n = nt * 64 + (chunk - 24) * 8 + srow;
      p = wuE + (size_t)n * HH + scol;
    }
    gp[c] = p;
  }
  f32x4 accG[4][2] = {}; f32x4 accU[4][2] = {};
  int quad = lane >> 4, colc = lane & 15;
  for (int k0 = 0; k0 < HH; k0 += 64) {
#pragma unroll
    for (int c = 0; c < 8; ++c) {
      int chunk = c * 4 + wv;
      u16* dst = (chunk < 16) ? &As[chunk * 512]
               : (chunk < 24) ? &Bg[(chunk - 16) * 512]
                              : &Bu[(chunk - 24) * 512];
      gl2lds16(gp[c] + k0, dst);
    }
    __syncthreads();
#pragma unroll
    for (int kk = 0; kk < 64; kk += 32) {
      int gl = (kk >> 3) + quad;            // logical k-group
      s16x8 a[4], bg[2], bu[2];
#pragma unroll
      for (int f = 0; f < 4; ++f) {
        int m = wm * 64 + f * 16 + colc;
        a[f] = *reinterpret_cast<const s16x8*>(&As[m * 64 + ((gl ^ (m & 7)) << 3)]);
      }
#pragma unroll
      for (int f = 0; f < 2; ++f) {
        int n = wn * 32 + f * 16 + colc;
        bg[f] = *reinterpret_cast<const s16x8*>(&Bg[n * 64 + ((gl ^ (n & 7)) << 3)]);
        bu[f] = *reinterpret_cast<const s16x8*>(&Bu[n * 64 + ((gl ^ (n & 7)) << 3)]);
      }
#pragma unroll
      for (int fm = 0; fm < 4; ++fm)
#pragma unroll
        for (int fn = 0; fn < 2; ++fn) {
          accG[fm][fn] = __builtin_amdgcn_mfma_f32_16x16x32_bf16(a[fm], bg[fn], accG[fm][fn], 0, 0, 0);
          accU[fm][fn] = __builtin_amdgcn_mfma_f32_16x16x32_bf16(a[fm], bu[fn], accU[fm][fn], 0, 0, 0);
        }
    }
    __syncthreads();
  }
  // epilogue: hidden = w_route * silu(g) * u   (C/D: col=lane&15, row=quad*4+reg)
  int hb = offsets[e];
#pragma unroll
  for (int fm = 0; fm < 4; ++fm) {
#pragma unroll
    for (int r = 0; r < 4; ++r) {
      int mi = mt * 128 + wm * 64 + fm * 16 + quad * 4 + r;
      if (mi < cnt) {
        float wr = wlist[e * TT + mi];
        u16* hrow = hidden + (size_t)(hb + mi) * II + nt * 64 + wn * 32;
#pragma unroll
        for (int fn = 0; fn < 2; ++fn) {
          float g = accG[fm][fn][r], u = accU[fm][fn][r];
          float hval = wr * u * g / (1.f + expf(-g));
          hrow[fn * 16 + colc] = f2bf(hval);
        }
      }
    }
  }
}

// ---------------- down GEMM: hidden @ wd^T -> dense bf16 rows in dtmp (no atomics) ----------------
// R9: retiled 128(M)x64(N) (was 128x128) — doubles working blocks to ~1024 (grid
// starvation was the limiter: ~1.4 blocks/CU avg), halves acc VGPRs, LDS 24 KB.
__global__ __launch_bounds__(256, 2) void down_kernel(
    const u16* __restrict__ hidden, const u16* __restrict__ wdt,
    const int* __restrict__ counts, const int* __restrict__ offsets,
    u16* __restrict__ dtmp) {
  int e = blockIdx.z, mt = blockIdx.y, nt = blockIdx.x;   // nt 0..15 (64 cols each)
  int cnt = counts[e];
  if (mt * 128 >= cnt) return;
  int hb = offsets[e];
  __shared__ u16 As[128 * 64];
  __shared__ u16 Bs[64 * 64];
  int tid = threadIdx.x, lane = tid & 63, wv = tid >> 6;
  int wm = wv >> 1, wn = wv & 1;
  int srow = lane >> 3;
  int scol = (((lane & 7) ^ srow)) * 8;     // swizzled global k-offset
  const u16* wdE = wdt + (size_t)e * HH * II;
  // 24 chunks of 8 rows: A=0..15, B=16..23
  const u16* gA[4]; const u16* gB[2];
#pragma unroll
  for (int c = 0; c < 4; ++c) {
    int chunk = c * 4 + wv;
    int row = hb + mt * 128 + chunk * 8 + srow;
    if (row > 8191) row = 8191;   // clamp pad rows into the hidden buffer
    gA[c] = hidden + (size_t)row * II + scol;
  }
#pragma unroll
  for (int c = 0; c < 2; ++c) {
    int n = nt * 64 + (c * 4 + wv) * 8 + srow;
    gB[c] = wdE + (size_t)n * II + scol;
  }
  f32x4 acc[4][2] = {};
  int quad = lane >> 4, colc = lane & 15;
  for (int k0 = 0; k0 < II; k0 += 64) {
#pragma unroll
    for (int c = 0; c < 4; ++c)
      gl2lds16(gA[c] + k0, &As[(c * 4 + wv) * 512]);
#pragma unroll
    for (int c = 0; c < 2; ++c)
      gl2lds16(gB[c] + k0, &Bs[(c * 4 + wv) * 512]);
    __syncthreads();
#pragma unroll
    for (int kk = 0; kk < 64; kk += 32) {
      int gl = (kk >> 3) + quad;
      s16x8 a[4], b[2];
#pragma unroll
      for (int f = 0; f < 4; ++f) {
        int m = wm * 64 + f * 16 + colc;
        a[f] = *reinterpret_cast<const s16x8*>(&As[m * 64 + ((gl ^ (m & 7)) << 3)]);
      }
#pragma unroll
      for (int f = 0; f < 2; ++f) {
        int n = wn * 32 + f * 16 + colc;
        b[f] = *reinterpret_cast<const s16x8*>(&Bs[n * 64 + ((gl ^ (n & 7)) << 3)]);
      }
#pragma unroll
      for (int fm = 0; fm < 4; ++fm)
#pragma unroll
        for (int fn = 0; fn < 2; ++fn)
          acc[fm][fn] = __builtin_amdgcn_mfma_f32_16x16x32_bf16(a[fm], b[fn], acc[fm][fn], 0, 0, 0);
    }
    __syncthreads();
  }
#pragma unroll
  for (int fm = 0; fm < 4; ++fm) {
#pragma unroll
    for (int r = 0; r < 4; ++r) {
      int mi = mt * 128 + wm * 64 + fm * 16 + quad * 4 + r;
      if (mi < cnt) {
        u16* drow = dtmp + (size_t)(hb + mi) * HH + nt * 64 + wn * 32;
#pragma unroll
        for (int fn = 0; fn < 2; ++fn)
          drow[fn * 16 + colc] = f2bf(acc[fm][fn][r]);
      }
    }
  }
}

// ---------------- combine: out[t] = sum of 4 expert rows (routing weight already applied) ----------------
__global__ void combine_kernel(const u16* __restrict__ dtmp, const int* __restrict__ rowof,
                               float* __restrict__ out) {
  int t = blockIdx.x, tid = threadIdx.x;
  int4 rw = reinterpret_cast<const int4*>(rowof)[t];
  int h = tid * 4;
  float s0 = 0.f, s1 = 0.f, s2 = 0.f, s3 = 0.f;
  int rows[4] = {rw.x, rw.y, rw.z, rw.w};
#pragma unroll
  for (int k = 0; k < 4; ++k) {
    ushort4 v = *reinterpret_cast<const ushort4*>(&dtmp[(size_t)rows[k] * HH + h]);
    s0 += bf2f(v.x); s1 += bf2f(v.y); s2 += bf2f(v.z); s3 += bf2f(v.w);
  }
  *reinterpret_cast<float4*>(&out[(size_t)t * HH + h]) = make_float4(s0, s1, s2, s3);
}

extern "C" void kernel_launch(void* const* d_in, const int* in_sizes, int n_in,
                              void* d_out, int out_size, void* d_ws, size_t ws_size,
                              hipStream_t stream) {
  const float* x   = (const float*)d_in[0];   // [1,2048,1024]
  const float* wg  = (const float*)d_in[1];   // [1024,16]
  const float* wgp = (const float*)d_in[2];   // [16,1024,512]
  const float* wup = (const float*)d_in[3];   // [16,1024,512]
  const float* wdp = (const float*)d_in[4];   // [16,512,1024]
  float* out = (float*)d_out;                 // [2048*1024] then router_logits [2048*16]
  float* rl  = out + (size_t)TT * HH;

  char* w = (char*)d_ws;
  int*      counts  = (int*)(w + 0);                  // 16 ints
  int*      offsets = (int*)(w + 64);                 // 17 ints
  unsigned* selmask = (unsigned*)(w + 1024);          // [T] packed 4x4-bit expert ids
  float*    wsel    = (float*)(w + 16384);            // [T][4] normalized weights (32 KB)
  int*      rowof   = (int*)(w + 49152);              // [T][4] global hidden-row ids (32 KB)
  int*      tlist   = (int*)(w + 81920);              // [E][T] token ids (128 KB)
  float*    wlist   = (float*)(w + 210944);           // [E][T] routing weights (128 KB)
  float*    wgT     = (float*)(w + 339968);           // [E][H] fp32 transposed router weights
  u16*      xb      = (u16*)(w + 405504);             // [T][H] bf16 (4 MB)
  u16*      wgt     = xb  + (size_t)TT * HH;          // [E][I][H] bf16 (transposed, 16 MB)
  u16*      wut     = wgt + (size_t)EE * II * HH;     // 16 MB
  u16*      wdt     = wut + (size_t)EE * II * HH;     // [E][H][I] bf16 (transposed, 16 MB)
  u16*      hidden  = wdt + (size_t)EE * HH * II;     // [8192][I] bf16 (8 MB)
  u16*      dtmp    = wgt;   // [8192][H] bf16 (16 MB) — safely aliases wgt: gateup
                             // (last reader of wgt) completes before down runs.

  hipLaunchKernelGGL(prep_kernel, dim3(12288 + 2048 + 64), dim3(256), 0, stream,
                     wgp, wup, wdp, wgt, wut, wdt, x, xb, wg, wgT);
  hipLaunchKernelGGL(router_kernel, dim3(TT / 4), dim3(256), 0, stream,
                     x, wgT, rl, selmask, wsel);
  hipLaunchKernelGGL(build_lists_kernel, dim3(1), dim3(1024), 0, stream,
                     selmask, wsel, counts, offsets, tlist, wlist, rowof);
  hipLaunchKernelGGL(gateup_kernel, dim3(8, 16, 16), dim3(256), 0, stream,
                     xb, wgt, wut, counts, offsets, tlist, wlist, hidden);
  hipLaunchKernelGGL(down_kernel, dim3(16, 16, 16), dim3(256), 0, stream,
                     hidden, wdt, counts, offsets, dtmp);
  hipLaunchKernelGGL(combine_kernel, dim3(TT), dim3(256), 0, stream,
                     dtmp, rowof, out);
}